// Round 8
// baseline (217.489 us; speedup 1.0000x reference)
//
#include <hip/hip_runtime.h>
#include <hip/hip_bf16.h>

#define B_ 32
#define S_ 4096
#define H_ 512

typedef short bf16x8 __attribute__((ext_vector_type(8)));
typedef float f32x4 __attribute__((ext_vector_type(4)));

__device__ inline unsigned short f2bf(float x) {
    unsigned u = __float_as_uint(x);
    return (unsigned short)((u + 0x7fffu + ((u >> 16) & 1u)) >> 16);
}

// native packed f32x2 -> bf16x2 (v_cvt_pk_bf16_f32, RNE)
__device__ __forceinline__ unsigned cvt2(float a, float b) {
    __hip_bfloat162 h = __float22bfloat162_rn(float2{a, b});
    return *reinterpret_cast<unsigned*>(&h);
}

__device__ inline float fast_tanh(float x) {
    float e = __expf(2.f * x);
    return 1.f - 2.f / (e + 1.f);
}

// async global->LDS, 16B per lane; lds base must be wave-uniform (HW adds lane*16)
__device__ __forceinline__ void stage16(const void* g, void* lds_base) {
    __builtin_amdgcn_global_load_lds(
        (const __attribute__((address_space(1))) unsigned char*)g,
        (__attribute__((address_space(3))) unsigned char*)lds_base, 16, 0, 0);
}

// ---------------------------------------------------------------------------
// Kernel 1: transpose+convert Ua[h][d] (f32) -> ua_t[d][h] (bf16, row-major)
// ---------------------------------------------------------------------------
__global__ void k_prep_ua(const float* __restrict__ Ua,
                          unsigned short* __restrict__ ua_t) {
    __shared__ float tile[32][33];
    int h0 = blockIdx.x * 32, d0 = blockIdx.y * 32;
    int tx = threadIdx.x, ty = threadIdx.y;
#pragma unroll
    for (int j = 0; j < 4; ++j)
        tile[ty + j * 8][tx] = Ua[(size_t)(h0 + ty + j * 8) * H_ + d0 + tx];
    __syncthreads();
#pragma unroll
    for (int j = 0; j < 4; ++j) {
        int dl = ty + j * 8;
        ua_t[(size_t)(d0 + dl) * H_ + h0 + tx] = f2bf(tile[tx][dl]);
    }
}

// ---------------------------------------------------------------------------
// Kernel 2: q_proj[b][d] = sum_h query[b][h] * Wa[h][d]   (fp32, tiny)
// ---------------------------------------------------------------------------
__global__ __launch_bounds__(512) void k_qproj(const float* __restrict__ query,
                                               const float* __restrict__ Wa,
                                               float* __restrict__ qproj) {
    __shared__ float q[H_];
    int b = blockIdx.x, d = threadIdx.x;
    q[d] = query[(size_t)b * H_ + d];
    __syncthreads();
    float acc = 0.f;
    for (int h = 0; h < H_; ++h)
        acc = fmaf(q[h], Wa[(size_t)h * H_ + d], acc);
    qproj[(size_t)b * H_ + d] = acc;
}

// ---------------------------------------------------------------------------
// Kernel 3: partial scores. R7 skeleton + T4 counted-vmcnt pipeline:
//  - raw s_barrier, NO vmcnt(0) drain in the main loop (the R1-R7 killer)
//  - B(t+1) via gload_lds into Bs[nxt], waited with vmcnt(8) at iter end
//  - depth-2 A reg pipeline: A(t+2) issued at iter t, cvt+ds_write at t+1
//  - lgkmcnt(0) before every barrier (ds_write visibility), uniform barriers
// flat grid 4096 = (b:32) x (m:32) x (nb:4), XCD-swizzled, nb fastest.
// ---------------------------------------------------------------------------
__global__ __launch_bounds__(256, 2) void k_scores(
    const float* __restrict__ keys, const unsigned short* __restrict__ ua_t,
    const float* __restrict__ qproj, const float* __restrict__ Va,
    float* __restrict__ part_sc) {
    __shared__ __align__(16) unsigned char As[2][16384];   // [128 rows][128 B] swizzled
    __shared__ __align__(16) unsigned char Bs[2][16384];
    __shared__ float smp[2][128];

    int tid = threadIdx.x;
    int wave = tid >> 6, lane = tid & 63;
    int lq = lane & 15, lh = lane >> 4;
    int wm = wave >> 1, wn = wave & 1;   // 2x2 wave grid, each 64x64

    int logical = (blockIdx.x & 7) * 512 + (blockIdx.x >> 3);
    int b  = logical >> 7;
    int m0 = ((logical >> 2) & 31) * 128;
    int nb = logical & 3;

    const float* keysb = keys + (size_t)b * S_ * H_;

    // A staging (coalesced): sweep j covers rows j*16..j*16+15; thread t:
    // row_in_sweep = t>>4, float col = (t&15)*4.
    int arow_t = tid >> 4;
    const float* aptr = keysb + (size_t)(m0 + arow_t) * H_ + (tid & 15) * 4;
    unsigned awb = (unsigned)(arow_t * 128 + (((tid & 15) * 8) ^ ((arow_t & 7) << 4)));

    // B staging: 4 gload_lds per wave; issue j=wave*4+i covers rows 8j..8j+7.
    int rbl = lane >> 3;
    unsigned cbb = (unsigned)(((lane & 7) * 16) ^ (rbl << 4));
    const unsigned char* uab = (const unsigned char*)ua_t;
    const unsigned char* bsrc[4];
    unsigned bdst[4];
#pragma unroll
    for (int i = 0; i < 4; ++i) {
        int j = wave * 4 + i;
        bsrc[i] = uab + ((size_t)(nb * 128 + 8 * j + rbl)) * 1024 + cbb;
        bdst[i] = (unsigned)(j * 1024);
    }

    f32x4 acc[4][4];
#pragma unroll
    for (int i = 0; i < 4; ++i)
#pragma unroll
        for (int j = 0; j < 4; ++j) acc[i][j] = (f32x4){0.f, 0.f, 0.f, 0.f};

    float4 arA[8], arB[8];

    auto loadA = [&](float4 (&arr)[8], int tt) {
#pragma unroll
        for (int j = 0; j < 8; ++j)
            arr[j] = *(const float4*)(aptr + (size_t)j * 16 * H_ + tt * 64);
    };
    auto writeA = [&](const float4 (&arr)[8], int buf) {
#pragma unroll
        for (int j = 0; j < 8; ++j) {
            uint2 w;
            w.x = cvt2(arr[j].x, arr[j].y);
            w.y = cvt2(arr[j].z, arr[j].w);
            *(uint2*)(&As[buf][0] + awb + j * 2048) = w;
        }
    };

    // ---- prologue: B(0)->Bs[0]; A(0)->arA; A(1)->arB; cvt A(0)->As[0]
#pragma unroll
    for (int i = 0; i < 4; ++i) stage16(bsrc[i], &Bs[0][bdst[i]]);
    loadA(arA, 0);
    loadA(arB, 1);
    writeA(arA, 0);                       // compiler waits A(0) only (B(0) older: also done)
    asm volatile("s_waitcnt lgkmcnt(0)" ::: "memory");
    __builtin_amdgcn_s_barrier();
    __builtin_amdgcn_sched_barrier(0);

#pragma unroll
    for (int t = 0; t < 8; ++t) {
        const int cur = t & 1, nxt = cur ^ 1;
        // 1) issue B(t+1) -> Bs[nxt] (readers of old Bs[nxt] finished at last barrier)
        if (t < 7) {
#pragma unroll
            for (int i = 0; i < 4; ++i)
                stage16(bsrc[i] + (t + 1) * 128, &Bs[nxt][bdst[i]]);
        }
        // 2) issue A(t+2) into the free reg set (consumed next iter -> full-iter cover)
        if (t < 6) {
            if ((t & 1) == 0) loadA(arA, t + 2); else loadA(arB, t + 2);
        }
        __builtin_amdgcn_sched_barrier(0);   // pin the 12 VMEM issues before compute
        // 3) cvt+write A(t+1) -> As[nxt] (regs loaded a full iteration ago)
        if (t < 7) {
            if ((t & 1) == 0) writeA(arB, nxt); else writeA(arA, nxt);
        }
        // 4) compute tile t: 16 ds_read_b128 -> 32 MFMAs per wave
#pragma unroll
        for (int ks = 0; ks < 2; ++ks) {
            bf16x8 af[4], bv[4];
            unsigned koff = (unsigned)(ks * 64 + lh * 16);
#pragma unroll
            for (int mf = 0; mf < 4; ++mf) {
                unsigned R = (unsigned)(wm * 64 + mf * 16 + lq);
                af[mf] = *(const bf16x8*)(&As[cur][0] + R * 128 + (koff ^ ((R & 7) << 4)));
            }
#pragma unroll
            for (int nf = 0; nf < 4; ++nf) {
                unsigned R = (unsigned)(wn * 64 + nf * 16 + lq);
                bv[nf] = *(const bf16x8*)(&Bs[cur][0] + R * 128 + (koff ^ ((R & 7) << 4)));
            }
#pragma unroll
            for (int mf = 0; mf < 4; ++mf)
#pragma unroll
                for (int nf = 0; nf < 4; ++nf)
                    acc[mf][nf] = __builtin_amdgcn_mfma_f32_16x16x32_bf16(
                        af[mf], bv[nf], acc[mf][nf], 0, 0, 0);
        }
        // 5) counted wait: B(t+1) retired (4 oldest); A(t+2) x8 STAY IN FLIGHT.
        //    lgkmcnt(0): this wave's ds_reads/ds_writes drained before barrier.
        if (t < 6) {
            asm volatile("s_waitcnt vmcnt(8) lgkmcnt(0)" ::: "memory");
        } else {
            asm volatile("s_waitcnt vmcnt(0) lgkmcnt(0)" ::: "memory");
        }
        __builtin_amdgcn_s_barrier();
        __builtin_amdgcn_sched_barrier(0);
    }

    // epilogue: partial score over this block's 128 d-columns
    float va_r[4], qp_r[4];
#pragma unroll
    for (int nf = 0; nf < 4; ++nf) {
        int n = nb * 128 + wn * 64 + nf * 16 + lq;
        va_r[nf] = Va[n];
        qp_r[nf] = qproj[(size_t)b * H_ + n];
    }
#pragma unroll
    for (int mf = 0; mf < 4; ++mf) {
#pragma unroll
        for (int reg = 0; reg < 4; ++reg) {
            float p = 0.f;
#pragma unroll
            for (int nf = 0; nf < 4; ++nf)
                p += va_r[nf] * fast_tanh(qp_r[nf] + acc[mf][nf][reg]);
            p += __shfl_xor(p, 1);
            p += __shfl_xor(p, 2);
            p += __shfl_xor(p, 4);
            p += __shfl_xor(p, 8);
            if (lq == 0) smp[wn][wm * 64 + mf * 16 + lh * 4 + reg] = p;
        }
    }
    __syncthreads();
    if (tid < 128) {
        float s = smp[0][tid] + smp[1][tid];
        part_sc[((size_t)nb * B_ + b) * S_ + m0 + tid] = s;
    }
}

// ---------------------------------------------------------------------------
// Kernel 4: merge 4 n-partials (fixed order, deterministic) + softmax -> wts
// ---------------------------------------------------------------------------
__global__ __launch_bounds__(512) void k_softmax(const float* __restrict__ part_sc,
                                                 float* __restrict__ wts) {
    __shared__ float red[8];
    int b = blockIdx.x, tid = threadIdx.x;
    const float* p0 = part_sc + (size_t)b * S_;
    const float* p1 = p0 + (size_t)B_ * S_;
    const float* p2 = p1 + (size_t)B_ * S_;
    const float* p3 = p2 + (size_t)B_ * S_;
    float v[8];
    float m = -1e30f;
#pragma unroll
    for (int i = 0; i < 8; ++i) {
        int s = tid + i * 512;
        v[i] = ((p0[s] + p1[s]) + (p2[s] + p3[s]));
        m = fmaxf(m, v[i]);
    }
#pragma unroll
    for (int o = 1; o < 64; o <<= 1) m = fmaxf(m, __shfl_xor(m, o));
    if ((tid & 63) == 0) red[tid >> 6] = m;
    __syncthreads();
    m = red[0];
#pragma unroll
    for (int w = 1; w < 8; ++w) m = fmaxf(m, red[w]);
    float sum = 0.f;
#pragma unroll
    for (int i = 0; i < 8; ++i) {
        v[i] = __expf(v[i] - m);
        sum += v[i];
    }
#pragma unroll
    for (int o = 1; o < 64; o <<= 1) sum += __shfl_xor(sum, o);
    __syncthreads();
    if ((tid & 63) == 0) red[tid >> 6] = sum;
    __syncthreads();
    float tot = 0.f;
#pragma unroll
    for (int w = 0; w < 8; ++w) tot += red[w];
    float inv = 1.f / tot;
#pragma unroll
    for (int i = 0; i < 8; ++i) wts[(size_t)b * S_ + tid + i * 512] = v[i] * inv;
}

// ---------------------------------------------------------------------------
// Kernel 5: partial context over 128-row chunks. grid (32,32), block (512)
// ---------------------------------------------------------------------------
__global__ __launch_bounds__(512) void k_ctx_part(const float* __restrict__ keys,
                                                  const float* __restrict__ wts,
                                                  float* __restrict__ part) {
    int c = blockIdx.x, b = blockIdx.y, h = threadIdx.x;
    const float* wrow = wts + (size_t)b * S_ + c * 128;
    const float* kbase = keys + ((size_t)b * S_ + c * 128) * H_ + h;
    float acc = 0.f;
#pragma unroll 8
    for (int s = 0; s < 128; ++s)
        acc = fmaf(wrow[s], kbase[(size_t)s * H_], acc);
    part[((size_t)c * B_ + b) * H_ + h] = acc;
}

// ---------------------------------------------------------------------------
// Kernel 6: reduce partials -> context. grid (32), block (512)
// ---------------------------------------------------------------------------
__global__ __launch_bounds__(512) void k_ctx_reduce(const float* __restrict__ part,
                                                    float* __restrict__ ctx) {
    int b = blockIdx.x, h = threadIdx.x;
    float s = 0.f;
#pragma unroll
    for (int c = 0; c < 32; ++c) s += part[((size_t)c * B_ + b) * H_ + h];
    ctx[(size_t)b * H_ + h] = s;
}

// ---------------------------------------------------------------------------
extern "C" void kernel_launch(void* const* d_in, const int* in_sizes, int n_in,
                              void* d_out, int out_size, void* d_ws, size_t ws_size,
                              hipStream_t stream) {
    const float* query = (const float*)d_in[0];
    const float* keys  = (const float*)d_in[1];
    const float* Wa    = (const float*)d_in[2];
    const float* Ua    = (const float*)d_in[3];
    const float* Va    = (const float*)d_in[4];

    float* out = (float*)d_out;
    float* ctx = out;             // [32,512]
    float* wts = out + B_ * H_;   // [32,4096]

    char* ws = (char*)d_ws;
    unsigned short* ua_t = (unsigned short*)ws;                     // 512 KB
    float* qproj   = (float*)(ws + 524288);                         // 64 KB
    float* part_sc = (float*)(ws + 524288 + 65536);                 // 2 MB
    float* part_cx = (float*)(ws + 524288 + 65536 + 2097152);       // 2 MB

    k_prep_ua<<<dim3(16, 16), dim3(32, 8), 0, stream>>>(Ua, ua_t);
    k_qproj<<<dim3(32), dim3(512), 0, stream>>>(query, Wa, qproj);
    k_scores<<<dim3(4096), dim3(256), 0, stream>>>(keys, ua_t, qproj, Va, part_sc);
    k_softmax<<<dim3(32), dim3(512), 0, stream>>>(part_sc, wts);
    k_ctx_part<<<dim3(32, 32), dim3(512), 0, stream>>>(keys, wts, part_cx);
    k_ctx_reduce<<<dim3(32), dim3(512), 0, stream>>>(part_cx, ctx);
}

// Round 9
// 211.390 us; speedup vs baseline: 1.0289x; 1.0289x over previous
//
#include <hip/hip_runtime.h>
#include <hip/hip_bf16.h>

#define B_ 32
#define S_ 4096
#define H_ 512

typedef short bf16x8 __attribute__((ext_vector_type(8)));
typedef float f32x4 __attribute__((ext_vector_type(4)));

__device__ inline unsigned short f2bf(float x) {
    unsigned u = __float_as_uint(x);
    return (unsigned short)((u + 0x7fffu + ((u >> 16) & 1u)) >> 16);
}

// native packed f32x2 -> bf16x2 (v_cvt_pk_bf16_f32, RNE)
__device__ __forceinline__ unsigned cvt2(float a, float b) {
    __hip_bfloat162 h = __float22bfloat162_rn(float2{a, b});
    return *reinterpret_cast<unsigned*>(&h);
}

__device__ inline float fast_tanh(float x) {
    float e = __expf(2.f * x);
    return 1.f - 2.f / (e + 1.f);
}

// async global->LDS, 16B per lane; lds base must be wave-uniform (HW adds lane*16)
__device__ __forceinline__ void stage16(const void* g, void* lds_base) {
    __builtin_amdgcn_global_load_lds(
        (const __attribute__((address_space(1))) unsigned char*)g,
        (__attribute__((address_space(3))) unsigned char*)lds_base, 16, 0, 0);
}

// ---------------------------------------------------------------------------
// Kernel 1: transpose+convert Ua[h][d] (f32) -> ua_t[d][h] (bf16, row-major)
// ---------------------------------------------------------------------------
__global__ void k_prep_ua(const float* __restrict__ Ua,
                          unsigned short* __restrict__ ua_t) {
    __shared__ float tile[32][33];
    int h0 = blockIdx.x * 32, d0 = blockIdx.y * 32;
    int tx = threadIdx.x, ty = threadIdx.y;
#pragma unroll
    for (int j = 0; j < 4; ++j)
        tile[ty + j * 8][tx] = Ua[(size_t)(h0 + ty + j * 8) * H_ + d0 + tx];
    __syncthreads();
#pragma unroll
    for (int j = 0; j < 4; ++j) {
        int dl = ty + j * 8;
        ua_t[(size_t)(d0 + dl) * H_ + h0 + tx] = f2bf(tile[tx][dl]);
    }
}

// ---------------------------------------------------------------------------
// Kernel 2: q_proj[b][d] = sum_h query[b][h] * Wa[h][d]   (fp32, tiny)
// ---------------------------------------------------------------------------
__global__ __launch_bounds__(512) void k_qproj(const float* __restrict__ query,
                                               const float* __restrict__ Wa,
                                               float* __restrict__ qproj) {
    __shared__ float q[H_];
    int b = blockIdx.x, d = threadIdx.x;
    q[d] = query[(size_t)b * H_ + d];
    __syncthreads();
    float acc = 0.f;
    for (int h = 0; h < H_; ++h)
        acc = fmaf(q[h], Wa[(size_t)h * H_ + d], acc);
    qproj[(size_t)b * H_ + d] = acc;
}

// ---------------------------------------------------------------------------
// Kernel 3: PERSISTENT partial-score blocks. 512 thr / 8 waves (2 wm x 4 wnn),
// wave tile 64x32. Block owns (b, nb, m-chunk of 1024 rows): 8 m-tiles x 8
// K-chunks(BK=64) = 64 main-loop iterations -> per-block fixed overhead
// (launch + prologue fill + epilogue) amortized 8x vs rounds 1-8.
// Grid = 512 blocks = exactly 2/CU resident = ONE dispatch generation.
// A/B dbuf LDS, one barrier/iter; B via global_load_lds (per-lane row +
// swizzle in global src); A reg-staged + cvt_pk (R7-proven addressing).
// Epilogue per m-tile runs after the loop barrier -> hides next staging.
// ---------------------------------------------------------------------------
__global__ __launch_bounds__(512, 4) void k_scores(
    const float* __restrict__ keys, const unsigned short* __restrict__ ua_t,
    const float* __restrict__ qproj, const float* __restrict__ Va,
    float* __restrict__ part_sc) {
    __shared__ __align__(16) unsigned char As[2][16384];   // [128 rows][128 B] swizzled
    __shared__ __align__(16) unsigned char Bs[2][16384];
    __shared__ float smp[4][128];

    int tid = threadIdx.x;
    int wave = tid >> 6, lane = tid & 63;
    int lq = lane & 15, lh = lane >> 4;
    int wm = wave >> 2;      // 0..1: row half (64 rows)
    int wnn = wave & 3;      // 0..3: col quarter (32 cols)

    // 512 blocks: XCD swizzle (512%8==0, 64/XCD); nb fastest -> the 4 n-tiles
    // sharing the same keys rows are XCD neighbors (L2 reuse).
    int logical = (blockIdx.x & 7) * 64 + (blockIdx.x >> 3);
    int nb = logical & 3;
    int bm = logical >> 2;         // 0..127 = b*4 + mchunk
    int b = bm >> 2;
    int mchunk = bm & 3;           // 1024-row chunk
    const float* keysb = keys + ((size_t)b * S_ + (size_t)mchunk * 1024) * H_;

    // --- A staging: sweep s covers rows 32s..32s+31; thread t: row 32s+(t>>4),
    // float col (t&15)*4. Wave instr = 4 rows x 256 B contiguous (16 lines).
    int ar = tid >> 4;             // 0..31
    int acf = (tid & 15) * 4;      // float col 0..60
    unsigned awb = (unsigned)(((tid & 15) * 8) ^ ((ar & 7) << 4));  // (32s keeps r&7)

    // --- B staging: 2 gload_lds per wave per chunk; instr j=wave*2+i covers
    // Bs rows 8j..8j+7. Per-lane src row 8j+(lane>>3), col (lane&7)*16,
    // XOR-swizzled by ((lane>>3)<<4). LDS dest linear.
    int rbl = lane >> 3;
    unsigned cbb = (unsigned)(((lane & 7) * 16) ^ (rbl << 4));
    const unsigned char* uab = (const unsigned char*)ua_t;
    const unsigned char* bsrc[2];
    unsigned bdst[2];
#pragma unroll
    for (int i = 0; i < 2; ++i) {
        int j = wave * 2 + i;
        bsrc[i] = uab + ((size_t)(nb * 128 + 8 * j + rbl)) * 1024 + cbb;
        bdst[i] = (unsigned)(j * 1024);
    }

    // per-block epilogue constants
    float va_r[2], qp_r[2];
#pragma unroll
    for (int nf = 0; nf < 2; ++nf) {
        int n = nb * 128 + wnn * 32 + nf * 16 + lq;
        va_r[nf] = Va[n];
        qp_r[nf] = qproj[(size_t)b * H_ + n];
    }

    f32x4 acc[4][2];
#pragma unroll
    for (int i = 0; i < 4; ++i)
#pragma unroll
        for (int j = 0; j < 2; ++j) acc[i][j] = (f32x4){0.f, 0.f, 0.f, 0.f};

    // ---- prologue: stage iteration 0 (mt=0, kk=0) into buffer 0
#pragma unroll
    for (int i = 0; i < 2; ++i) stage16(bsrc[i], &Bs[0][bdst[i]]);
    {
        const float* ap = keysb + (size_t)ar * H_ + acf;
#pragma unroll
        for (int s = 0; s < 4; ++s) {
            float4 v = *(const float4*)(ap + (size_t)(32 * s) * H_);
            uint2 w;
            w.x = cvt2(v.x, v.y);
            w.y = cvt2(v.z, v.w);
            *(uint2*)(&As[0][0] + (unsigned)((ar + 32 * s) * 128) + awb) = w;
        }
    }
    __syncthreads();

    // ---- main loop: g = 0..63; mt = g>>3, kk = g&7
#pragma unroll 2
    for (int g = 0; g < 64; ++g) {
        const int cur = g & 1, nxt = cur ^ 1;
        float4 av[4];
        // 1) issue next-chunk loads (fly across the compute phase)
        if (g < 63) {
            int g1 = g + 1;
            int kk1 = g1 & 7, mt1 = g1 >> 3;
#pragma unroll
            for (int i = 0; i < 2; ++i)
                stage16(bsrc[i] + kk1 * 128, &Bs[nxt][bdst[i]]);
            const float* ap = keysb + (size_t)(mt1 * 128 + ar) * H_ + kk1 * 64 + acf;
#pragma unroll
            for (int s = 0; s < 4; ++s)
                av[s] = *(const float4*)(ap + (size_t)(32 * s) * H_);
        }
        // 2) compute chunk g: 6 ds_read_b128 -> 16 MFMAs per wave per ks
#pragma unroll
        for (int ks = 0; ks < 2; ++ks) {
            bf16x8 af[4], bv[2];
            unsigned koff = (unsigned)(ks * 64 + lh * 16);
#pragma unroll
            for (int mf = 0; mf < 4; ++mf) {
                unsigned R = (unsigned)(wm * 64 + mf * 16 + lq);
                af[mf] = *(const bf16x8*)(&As[cur][0] + R * 128 + (koff ^ ((R & 7) << 4)));
            }
#pragma unroll
            for (int nf = 0; nf < 2; ++nf) {
                unsigned R = (unsigned)(wnn * 32 + nf * 16 + lq);
                bv[nf] = *(const bf16x8*)(&Bs[cur][0] + R * 128 + (koff ^ ((R & 7) << 4)));
            }
#pragma unroll
            for (int mf = 0; mf < 4; ++mf)
#pragma unroll
                for (int nf = 0; nf < 2; ++nf)
                    acc[mf][nf] = __builtin_amdgcn_mfma_f32_16x16x32_bf16(
                        af[mf], bv[nf], acc[mf][nf], 0, 0, 0);
        }
        // 3) cvt + write next A chunk
        if (g < 63) {
#pragma unroll
            for (int s = 0; s < 4; ++s) {
                uint2 w;
                w.x = cvt2(av[s].x, av[s].y);
                w.y = cvt2(av[s].z, av[s].w);
                *(uint2*)(&As[nxt][0] + (unsigned)((ar + 32 * s) * 128) + awb) = w;
            }
        }
        // 4) one barrier per iter (drains gload_lds vmcnt + A ds_writes)
        __syncthreads();
        // 5) end of m-tile: epilogue (overlaps next m-tile's in-flight staging)
        if ((g & 7) == 7) {
            int mt = g >> 3;
#pragma unroll
            for (int mf = 0; mf < 4; ++mf) {
#pragma unroll
                for (int reg = 0; reg < 4; ++reg) {
                    float p = va_r[0] * fast_tanh(qp_r[0] + acc[mf][0][reg])
                            + va_r[1] * fast_tanh(qp_r[1] + acc[mf][1][reg]);
                    p += __shfl_xor(p, 1);
                    p += __shfl_xor(p, 2);
                    p += __shfl_xor(p, 4);
                    p += __shfl_xor(p, 8);
                    if (lq == 0) smp[wnn][wm * 64 + mf * 16 + lh * 4 + reg] = p;
                }
#pragma unroll
                for (int nf = 0; nf < 2; ++nf)
                    acc[mf][nf] = (f32x4){0.f, 0.f, 0.f, 0.f};
            }
            __syncthreads();
            if (tid < 128) {
                float s = smp[0][tid] + smp[1][tid] + smp[2][tid] + smp[3][tid];
                part_sc[((size_t)nb * B_ + b) * S_ + mchunk * 1024 + mt * 128 + tid] = s;
            }
        }
    }
}

// ---------------------------------------------------------------------------
// Kernel 4: merge 4 n-partials (fixed order, deterministic) + softmax -> wts
// ---------------------------------------------------------------------------
__global__ __launch_bounds__(512) void k_softmax(const float* __restrict__ part_sc,
                                                 float* __restrict__ wts) {
    __shared__ float red[8];
    int b = blockIdx.x, tid = threadIdx.x;
    const float* p0 = part_sc + (size_t)b * S_;
    const float* p1 = p0 + (size_t)B_ * S_;
    const float* p2 = p1 + (size_t)B_ * S_;
    const float* p3 = p2 + (size_t)B_ * S_;
    float v[8];
    float m = -1e30f;
#pragma unroll
    for (int i = 0; i < 8; ++i) {
        int s = tid + i * 512;
        v[i] = ((p0[s] + p1[s]) + (p2[s] + p3[s]));
        m = fmaxf(m, v[i]);
    }
#pragma unroll
    for (int o = 1; o < 64; o <<= 1) m = fmaxf(m, __shfl_xor(m, o));
    if ((tid & 63) == 0) red[tid >> 6] = m;
    __syncthreads();
    m = red[0];
#pragma unroll
    for (int w = 1; w < 8; ++w) m = fmaxf(m, red[w]);
    float sum = 0.f;
#pragma unroll
    for (int i = 0; i < 8; ++i) {
        v[i] = __expf(v[i] - m);
        sum += v[i];
    }
#pragma unroll
    for (int o = 1; o < 64; o <<= 1) sum += __shfl_xor(sum, o);
    __syncthreads();
    if ((tid & 63) == 0) red[tid >> 6] = sum;
    __syncthreads();
    float tot = 0.f;
#pragma unroll
    for (int w = 0; w < 8; ++w) tot += red[w];
    float inv = 1.f / tot;
#pragma unroll
    for (int i = 0; i < 8; ++i) wts[(size_t)b * S_ + tid + i * 512] = v[i] * inv;
}

// ---------------------------------------------------------------------------
// Kernel 5: partial context over 128-row chunks. grid (32,32), block (512)
// ---------------------------------------------------------------------------
__global__ __launch_bounds__(512) void k_ctx_part(const float* __restrict__ keys,
                                                  const float* __restrict__ wts,
                                                  float* __restrict__ part) {
    int c = blockIdx.x, b = blockIdx.y, h = threadIdx.x;
    const float* wrow = wts + (size_t)b * S_ + c * 128;
    const float* kbase = keys + ((size_t)b * S_ + c * 128) * H_ + h;
    float acc = 0.f;
#pragma unroll 8
    for (int s = 0; s < 128; ++s)
        acc = fmaf(wrow[s], kbase[(size_t)s * H_], acc);
    part[((size_t)c * B_ + b) * H_ + h] = acc;
}

// ---------------------------------------------------------------------------
// Kernel 6: reduce partials -> context. grid (32), block (512)
// ---------------------------------------------------------------------------
__global__ __launch_bounds__(512) void k_ctx_reduce(const float* __restrict__ part,
                                                    float* __restrict__ ctx) {
    int b = blockIdx.x, h = threadIdx.x;
    float s = 0.f;
#pragma unroll
    for (int c = 0; c < 32; ++c) s += part[((size_t)c * B_ + b) * H_ + h];
    ctx[(size_t)b * H_ + h] = s;
}

// ---------------------------------------------------------------------------
extern "C" void kernel_launch(void* const* d_in, const int* in_sizes, int n_in,
                              void* d_out, int out_size, void* d_ws, size_t ws_size,
                              hipStream_t stream) {
    const float* query = (const float*)d_in[0];
    const float* keys  = (const float*)d_in[1];
    const float* Wa    = (const float*)d_in[2];
    const float* Ua    = (const float*)d_in[3];
    const float* Va    = (const float*)d_in[4];

    float* out = (float*)d_out;
    float* ctx = out;             // [32,512]
    float* wts = out + B_ * H_;   // [32,4096]

    char* ws = (char*)d_ws;
    unsigned short* ua_t = (unsigned short*)ws;                     // 512 KB
    float* qproj   = (float*)(ws + 524288);                         // 64 KB
    float* part_sc = (float*)(ws + 524288 + 65536);                 // 2 MB
    float* part_cx = (float*)(ws + 524288 + 65536 + 2097152);       // 2 MB

    k_prep_ua<<<dim3(16, 16), dim3(32, 8), 0, stream>>>(Ua, ua_t);
    k_qproj<<<dim3(32), dim3(512), 0, stream>>>(query, Wa, qproj);
    k_scores<<<dim3(512), dim3(512), 0, stream>>>(keys, ua_t, qproj, Va, part_sc);
    k_softmax<<<dim3(32), dim3(512), 0, stream>>>(part_sc, wts);
    k_ctx_part<<<dim3(32, 32), dim3(512), 0, stream>>>(keys, wts, part_cx);
    k_ctx_reduce<<<dim3(32), dim3(512), 0, stream>>>(part_cx, ctx);
}